// Round 8
// baseline (8352.811 us; speedup 1.0000x reference)
//
#include <hip/hip_runtime.h>

#define HID  64
#define TLEN 1024
#define NGATE 256   // 4*HID
#define LOG2E 1.4426950408889634f

__device__ __forceinline__ float fast_rcp(float x) { return __builtin_amdgcn_rcpf(x); }
__device__ __forceinline__ float fexp2(float x)    { return __builtin_amdgcn_exp2f(x); }

// sigmoid(x) = 1/(1+2^(-x*log2e))   : mul, exp2, add, rcp
__device__ __forceinline__ float fsig(float x) {
    return fast_rcp(1.0f + fexp2(-LOG2E * x));
}
// tanh(x) = 1 - 2/(1+2^(2x*log2e))  : mul, exp2, add, rcp, fma (branch-free,
// graceful at +-inf: exp2->inf => rcp->0 => 1; exp2->0 => -1)
__device__ __forceinline__ float ftanh(float x) {
    return fmaf(-2.0f, fast_rcp(1.0f + fexp2((2.0f * LOG2E) * x)), 1.0f);
}

// One workgroup per batch element (grid=256=#CUs). 1024 threads = 16 waves.
//   role = tid>>8:  0: g0 rows (W_hh0+W_ih0)   waves 0-3
//                   1: u1 rows (W_ih1)          waves 4-7
//                   2: v1 rows (W_hh1)          waves 8-11
//                   3: projection waves 12,13,14 (o = wv-12); wave 15 idle
//
// R3-R5 lesson: dur was invariant (2250us) across VGPR 64->84 and VALUBusy
// 45->37% -> latency-serialized on wave1's chain (shfl reduce + store drain +
// 2 barriers/step), NOT issue-bound. This version: ONE barrier per step
// (redundant per-wave gate combine into wave-private LDS h-buffers, parity
// double-buffered gate arrays), zero global ops on role-wave paths (x staged
// in LDS; projection + store on dedicated waves, drain hidden by next dot).
//
// Schedule (one iter): DOT(t) -> barrier -> COMBINE(t).
//   DOT(t):    role0 g0(t)=W@[x(t),h0(t-1)]; role1 u1(t)=W@h0(t-1);
//              role2 v1(t)=W@h1(t-2)         (reads wave-PRIVATE h bufs)
//   COMBINE(t): waves 0-7: h0(t) from g0(t) (redundant, lane j = elem j)
//               waves 8-11: h1(t-1) from u1(t)+v1(t); wave8 also -> ring
//               waves 12-14: out(t-2) = W_out@ring[t-2] (shfl reduce + store)
// Cross-wave data crosses exactly one barrier; parity buffers make the
// single barrier sufficient (wave skew < 1 iteration).
__global__ __launch_bounds__(1024)
__attribute__((amdgpu_waves_per_eu(4, 4)))
void lstm_fused(const float* __restrict__ x,
                const float* __restrict__ W_ih0, const float* __restrict__ W_hh0,
                const float* __restrict__ b_ih0, const float* __restrict__ b_hh0,
                const float* __restrict__ W_ih1, const float* __restrict__ W_hh1,
                const float* __restrict__ b_ih1, const float* __restrict__ b_hh1,
                const float* __restrict__ W_out, const float* __restrict__ b_out,
                float* __restrict__ out)
{
    __shared__ __align__(16) float x_lds[TLEN * 3];     // 12 KB
    __shared__ __align__(16) float g0buf[2][NGATE];     // 2 KB (parity dbuf)
    __shared__ __align__(16) float u1buf[2][NGATE];     // 2 KB
    __shared__ __align__(16) float v1buf[2][NGATE];     // 2 KB
    __shared__ __align__(16) float h0priv[8][HID];      // 2 KB (waves 0-7)
    __shared__ __align__(16) float h1priv[4][HID];      // 1 KB (waves 8-11)
    __shared__ __align__(16) float ring[4][HID];        // 1 KB (h1 history)

    const int tid  = threadIdx.x;
    const int lane = tid & 63;
    const int wv   = tid >> 6;      // 0..15
    const int role = tid >> 8;      // 0..3
    const int r    = tid & 255;
    const int bidx = blockIdx.x;

    const float* xb = x   + (size_t)bidx * TLEN * 3;
    float*       ob = out + (size_t)bidx * TLEN * 3;

    // ---- weight row into registers (64 VGPRs) ----
    const float* wrow;
    float bias = 0.0f, wi0 = 0.f, wi1 = 0.f, wi2 = 0.f;
    if (role == 0) {
        wrow = W_hh0 + r * HID; bias = b_ih0[r] + b_hh0[r];
        wi0 = W_ih0[r*3+0]; wi1 = W_ih0[r*3+1]; wi2 = W_ih0[r*3+2];
    } else if (role == 1) {
        wrow = W_ih1 + r * HID; bias = b_ih1[r] + b_hh1[r];
    } else {  // role 2 and (harmlessly) role 3
        wrow = W_hh1 + r * HID;
    }
    float w[HID];
    #pragma unroll
    for (int k4 = 0; k4 < HID / 4; ++k4) {
        float4 v = reinterpret_cast<const float4*>(wrow)[k4];
        w[4*k4+0] = v.x; w[4*k4+1] = v.y; w[4*k4+2] = v.z; w[4*k4+3] = v.w;
    }
    #pragma unroll
    for (int k = 0; k < HID; ++k) asm volatile("" : "+v"(w[k]));  // keep resident

    // projection waves' weights
    const int po = wv - 12;   // 0,1,2 valid; wave 15 -> 3 (idle)
    float wo = 0.f, bo = 0.f;
    if (role == 3 && po < 3) { wo = W_out[po * HID + lane]; bo = b_out[po]; }

    // ---- stage x into LDS (768 float4 = 3072 floats) ----
    if (tid < (TLEN * 3) / 4)
        reinterpret_cast<float4*>(x_lds)[tid] = reinterpret_cast<const float4*>(xb)[tid];
    if (tid < 8 * HID) (&h0priv[0][0])[tid] = 0.0f;
    if (tid < 4 * HID) { (&h1priv[0][0])[tid] = 0.0f; (&ring[0][0])[tid] = 0.0f; }
    float cst = 0.0f;   // c0[lane] for waves 0-7, c1[lane] for waves 8-11
    __syncthreads();

    float x0 = 0.f, x1 = 0.f, x2 = 0.f;
    if (role == 0) { x0 = x_lds[0]; x1 = x_lds[1]; x2 = x_lds[2]; }

    for (int t = 0; t <= TLEN + 1; ++t) {
        const int par = t & 1;
        // ================= DOT phase =================
        if (role == 0) {
            if (t < TLEN) {
                const float4* h4 = reinterpret_cast<const float4*>(h0priv[wv]);
                float a0 = fmaf(wi0, x0, bias);
                float a1 = wi1 * x1, a2 = wi2 * x2, a3 = 0.0f;
                #pragma unroll
                for (int k4 = 0; k4 < HID / 4; ++k4) {
                    float4 hv = h4[k4];
                    a0 = fmaf(w[4*k4+0], hv.x, a0);
                    a1 = fmaf(w[4*k4+1], hv.y, a1);
                    a2 = fmaf(w[4*k4+2], hv.z, a2);
                    a3 = fmaf(w[4*k4+3], hv.w, a3);
                }
                g0buf[par][r] = (a0 + a1) + (a2 + a3);
            }
        } else if (role == 1) {
            if (t <= TLEN) {
                const float4* h4 = reinterpret_cast<const float4*>(h0priv[wv]);
                float a0 = bias, a1 = 0.f, a2 = 0.f, a3 = 0.f;
                #pragma unroll
                for (int k4 = 0; k4 < HID / 4; ++k4) {
                    float4 hv = h4[k4];
                    a0 = fmaf(w[4*k4+0], hv.x, a0);
                    a1 = fmaf(w[4*k4+1], hv.y, a1);
                    a2 = fmaf(w[4*k4+2], hv.z, a2);
                    a3 = fmaf(w[4*k4+3], hv.w, a3);
                }
                u1buf[par][r] = (a0 + a1) + (a2 + a3);
            }
        } else if (role == 2) {
            if (t <= TLEN) {
                const float4* h4 = reinterpret_cast<const float4*>(h1priv[wv - 8]);
                float a0 = 0.f, a1 = 0.f, a2 = 0.f, a3 = 0.f;
                #pragma unroll
                for (int k4 = 0; k4 < HID / 4; ++k4) {
                    float4 hv = h4[k4];
                    a0 = fmaf(w[4*k4+0], hv.x, a0);
                    a1 = fmaf(w[4*k4+1], hv.y, a1);
                    a2 = fmaf(w[4*k4+2], hv.z, a2);
                    a3 = fmaf(w[4*k4+3], hv.w, a3);
                }
                v1buf[par][r] = (a0 + a1) + (a2 + a3);
            }
        }
        __syncthreads();
        // ================= COMBINE phase =================
        if (role <= 1) {                     // waves 0-7: layer-0 combine
            if (t < TLEN) {
                float gi = fsig (g0buf[par][lane]);
                float gf = fsig (g0buf[par][ 64 + lane]);
                float gg = ftanh(g0buf[par][128 + lane]);
                float go = fsig (g0buf[par][192 + lane]);
                cst = fmaf(gf, cst, gi * gg);
                h0priv[wv][lane] = go * ftanh(cst);
                if (role == 0) {             // prefetch x[t+1]
                    int tx = (t + 1 < TLEN) ? t + 1 : 0;
                    x0 = x_lds[3*tx]; x1 = x_lds[3*tx+1]; x2 = x_lds[3*tx+2];
                }
            }
        } else if (role == 2) {              // waves 8-11: layer-1 combine
            if (t >= 1 && t <= TLEN) {
                float gi = fsig (u1buf[par][lane]       + v1buf[par][lane]);
                float gf = fsig (u1buf[par][ 64 + lane] + v1buf[par][ 64 + lane]);
                float gg = ftanh(u1buf[par][128 + lane] + v1buf[par][128 + lane]);
                float go = fsig (u1buf[par][192 + lane] + v1buf[par][192 + lane]);
                cst = fmaf(gf, cst, gi * gg);
                float h = go * ftanh(cst);
                h1priv[wv - 8][lane] = h;
                if (wv == 8) ring[(t - 1) & 3][lane] = h;   // h1[t-1]
            }
        } else if (po < 3) {                 // waves 12-14: project out[t-2]
            if (t >= 2) {
                float p = wo * ring[(t - 2) & 3][lane];
                #pragma unroll
                for (int off = 32; off > 0; off >>= 1) p += __shfl_xor(p, off);
                if (lane == 0) ob[(size_t)(t - 2) * 3 + po] = p + bo;
            }
        }
        // no second barrier: next DOT reads only wave-private h bufs;
        // shared g/u/v are parity double-buffered (skew < 1 iter).
    }
}

extern "C" void kernel_launch(void* const* d_in, const int* in_sizes, int n_in,
                              void* d_out, int out_size, void* d_ws, size_t ws_size,
                              hipStream_t stream) {
    const float* x     = (const float*)d_in[0];
    const float* W_ih0 = (const float*)d_in[1];
    const float* W_hh0 = (const float*)d_in[2];
    const float* b_ih0 = (const float*)d_in[3];
    const float* b_hh0 = (const float*)d_in[4];
    const float* W_ih1 = (const float*)d_in[5];
    const float* W_hh1 = (const float*)d_in[6];
    const float* b_ih1 = (const float*)d_in[7];
    const float* b_hh1 = (const float*)d_in[8];
    const float* W_out = (const float*)d_in[9];
    const float* b_out = (const float*)d_in[10];
    float* out = (float*)d_out;

    const int B = in_sizes[0] / (TLEN * 3);   // 256
    hipLaunchKernelGGL(lstm_fused, dim3(B), dim3(1024), 0, stream,
                       x, W_ih0, W_hh0, b_ih0, b_hh0,
                       W_ih1, W_hh1, b_ih1, b_hh1, W_out, b_out, out);
}

// Round 9
// 7659.247 us; speedup vs baseline: 1.0906x; 1.0906x over previous
//
#include <hip/hip_runtime.h>

#define HID   64
#define TLEN  1024
#define NGATE 256   // 4*HID
#define RINGD 32    // h1 history ring depth
#define RINGP 65    // padded cols (bank spread)
#define LOG2E 1.4426950408889634f

__device__ __forceinline__ float fast_rcp(float x) { return __builtin_amdgcn_rcpf(x); }
__device__ __forceinline__ float fexp2(float x)    { return __builtin_amdgcn_exp2f(x); }

__device__ __forceinline__ float fsig(float x) {
    return fast_rcp(1.0f + fexp2(-LOG2E * x));
}
__device__ __forceinline__ float ftanh(float x) {
    return fmaf(-2.0f, fast_rcp(1.0f + fexp2((2.0f * LOG2E) * x)), 1.0f);
}

// One workgroup per batch element (grid=256=#CUs). 768 threads = 12 waves,
// EXACTLY 3 waves/EU -- the (3,3)+768 combo measured VGPR=84 (weights
// register-resident). 1024thr/(4,4) re-triggered the 64-VGPR cap and a
// 7.5GB scratch storm (R8: 8353us). Do not change this geometry casually.
//
//   waves 0-3  (role0): g0 rows r=tid&255 (W_hh0 row + W_ih0[r][:], bias)
//   waves 4-7  (role1): u1 rows (W_ih1 row, bias)
//   waves 8-11 (role2): v1 rows (W_hh1 row); waves 9-11 also own output
//                       component o=wv-9 for the batched projection
//
// Single barrier per step: DOT(t) -> barrier -> COMBINE(t).
//   DOT(t):    role0 g0(t); role1 u1(t) from h0(t-1); role2 v1(t) from h1(t-2)
//              (h read from wave-PRIVATE LDS copies; gate bufs parity-dbuf'd)
//   COMBINE(t): waves 0-7 redundantly combine layer0 -> own h0priv (t<TLEN)
//               waves 8-11 redundantly combine layer1 -> own h1priv (1<=t<=TLEN);
//                 wave 8 also writes h1[t-1] -> ring[(t-1)&31]
//               waves 9-11, every 16 steps (t%16==1, t>=17): batched projection
//                 out[s][o] for s in [t-17, t-2] via transposed matvec on ring
//                 (lane=tau+16q: 16-elem partial dot, 2-level shfl reduce).
//                 Newest slot read (t-2) crossed >=1 barrier; slot being
//                 written (t-1) is not in the read set; overwrite horizon 31.
__global__ __launch_bounds__(768)
__attribute__((amdgpu_waves_per_eu(3, 3)))
void lstm_fused(const float* __restrict__ x,
                const float* __restrict__ W_ih0, const float* __restrict__ W_hh0,
                const float* __restrict__ b_ih0, const float* __restrict__ b_hh0,
                const float* __restrict__ W_ih1, const float* __restrict__ W_hh1,
                const float* __restrict__ b_ih1, const float* __restrict__ b_hh1,
                const float* __restrict__ W_out, const float* __restrict__ b_out,
                float* __restrict__ out)
{
    __shared__ __align__(16) float x_lds[TLEN * 3];     // 12 KB
    __shared__ __align__(16) float g0buf[2][NGATE];     // 2 KB (parity dbuf)
    __shared__ __align__(16) float u1buf[2][NGATE];     // 2 KB
    __shared__ __align__(16) float v1buf[2][NGATE];     // 2 KB
    __shared__ __align__(16) float h0priv[8][HID];      // 2 KB (waves 0-7)
    __shared__ __align__(16) float h1priv[4][HID];      // 1 KB (waves 8-11)
    __shared__ __align__(16) float ring[RINGD][RINGP];  // 8.1 KB h1 history

    const int tid  = threadIdx.x;
    const int lane = tid & 63;
    const int wv   = tid >> 6;      // 0..11
    const int role = tid >> 8;      // 0..2
    const int r    = tid & 255;
    const int bidx = blockIdx.x;

    const float* xb = x   + (size_t)bidx * TLEN * 3;
    float*       ob = out + (size_t)bidx * TLEN * 3;

    // ---- weight row into registers (64 VGPRs) ----
    const float* wrow;
    float bias = 0.0f, wi0 = 0.f, wi1 = 0.f, wi2 = 0.f;
    if (role == 0) {
        wrow = W_hh0 + r * HID; bias = b_ih0[r] + b_hh0[r];
        wi0 = W_ih0[r*3+0]; wi1 = W_ih0[r*3+1]; wi2 = W_ih0[r*3+2];
    } else if (role == 1) {
        wrow = W_ih1 + r * HID; bias = b_ih1[r] + b_hh1[r];
    } else {
        wrow = W_hh1 + r * HID;
    }
    float w[HID];
    #pragma unroll
    for (int k4 = 0; k4 < HID / 4; ++k4) {
        float4 v = reinterpret_cast<const float4*>(wrow)[k4];
        w[4*k4+0] = v.x; w[4*k4+1] = v.y; w[4*k4+2] = v.z; w[4*k4+3] = v.w;
    }
    #pragma unroll
    for (int k = 0; k < HID; ++k) asm volatile("" : "+v"(w[k]));

    // projection weights for waves 9-11: lane tau+16q holds W_out[o][16q..16q+16)
    float wproj[16];
    float bo = 0.f;
    {
        const int o = wv - 9;
        const int q = lane >> 4;
        if (o >= 0 && o < 3) {
            #pragma unroll
            for (int i = 0; i < 16; ++i) wproj[i] = W_out[o * HID + q * 16 + i];
            bo = b_out[o];
        } else {
            #pragma unroll
            for (int i = 0; i < 16; ++i) wproj[i] = 0.f;
        }
    }
    #pragma unroll
    for (int i = 0; i < 16; ++i) asm volatile("" : "+v"(wproj[i]));

    // ---- stage x into LDS; init h bufs ----
    if (tid < (TLEN * 3) / 4)
        reinterpret_cast<float4*>(x_lds)[tid] = reinterpret_cast<const float4*>(xb)[tid];
    if (tid < 8 * HID) (&h0priv[0][0])[tid] = 0.0f;
    if (tid < 4 * HID) (&h1priv[0][0])[tid] = 0.0f;
    float cst = 0.0f;   // c0 for waves 0-7, c1 for waves 8-11 (per-lane elem)
    __syncthreads();

    float x0 = 0.f, x1 = 0.f, x2 = 0.f;
    if (role == 0) { x0 = x_lds[0]; x1 = x_lds[1]; x2 = x_lds[2]; }

    for (int t = 0; t <= TLEN + 1; ++t) {
        const int par = t & 1;
        // ================= DOT phase =================
        if (role == 0) {
            if (t < TLEN) {
                const float4* h4 = reinterpret_cast<const float4*>(h0priv[wv]);
                float a0 = fmaf(wi0, x0, bias);
                float a1 = wi1 * x1, a2 = wi2 * x2, a3 = 0.0f;
                #pragma unroll
                for (int k4 = 0; k4 < HID / 4; ++k4) {
                    float4 hv = h4[k4];
                    a0 = fmaf(w[4*k4+0], hv.x, a0);
                    a1 = fmaf(w[4*k4+1], hv.y, a1);
                    a2 = fmaf(w[4*k4+2], hv.z, a2);
                    a3 = fmaf(w[4*k4+3], hv.w, a3);
                }
                g0buf[par][r] = (a0 + a1) + (a2 + a3);
            }
        } else if (role == 1) {
            if (t <= TLEN) {
                const float4* h4 = reinterpret_cast<const float4*>(h0priv[wv]);
                float a0 = bias, a1 = 0.f, a2 = 0.f, a3 = 0.f;
                #pragma unroll
                for (int k4 = 0; k4 < HID / 4; ++k4) {
                    float4 hv = h4[k4];
                    a0 = fmaf(w[4*k4+0], hv.x, a0);
                    a1 = fmaf(w[4*k4+1], hv.y, a1);
                    a2 = fmaf(w[4*k4+2], hv.z, a2);
                    a3 = fmaf(w[4*k4+3], hv.w, a3);
                }
                u1buf[par][r] = (a0 + a1) + (a2 + a3);
            }
        } else {
            if (t <= TLEN) {
                const float4* h4 = reinterpret_cast<const float4*>(h1priv[wv - 8]);
                float a0 = 0.f, a1 = 0.f, a2 = 0.f, a3 = 0.f;
                #pragma unroll
                for (int k4 = 0; k4 < HID / 4; ++k4) {
                    float4 hv = h4[k4];
                    a0 = fmaf(w[4*k4+0], hv.x, a0);
                    a1 = fmaf(w[4*k4+1], hv.y, a1);
                    a2 = fmaf(w[4*k4+2], hv.z, a2);
                    a3 = fmaf(w[4*k4+3], hv.w, a3);
                }
                v1buf[par][r] = (a0 + a1) + (a2 + a3);
            }
        }
        __syncthreads();
        // ================= COMBINE phase =================
        if (role <= 1) {                     // waves 0-7: layer-0 combine
            if (t < TLEN) {
                float gi = fsig (g0buf[par][lane]);
                float gf = fsig (g0buf[par][ 64 + lane]);
                float gg = ftanh(g0buf[par][128 + lane]);
                float go = fsig (g0buf[par][192 + lane]);
                cst = fmaf(gf, cst, gi * gg);
                h0priv[wv][lane] = go * ftanh(cst);
                if (role == 0) {             // prefetch x[t+1]
                    int tx = (t + 1 < TLEN) ? t + 1 : 0;
                    x0 = x_lds[3*tx]; x1 = x_lds[3*tx+1]; x2 = x_lds[3*tx+2];
                }
            }
        } else {                             // waves 8-11: layer-1 combine
            if (t >= 1 && t <= TLEN) {
                float gi = fsig (u1buf[par][lane]       + v1buf[par][lane]);
                float gf = fsig (u1buf[par][ 64 + lane] + v1buf[par][ 64 + lane]);
                float gg = ftanh(u1buf[par][128 + lane] + v1buf[par][128 + lane]);
                float go = fsig (u1buf[par][192 + lane] + v1buf[par][192 + lane]);
                cst = fmaf(gf, cst, gi * gg);
                float h = go * ftanh(cst);
                h1priv[wv - 8][lane] = h;
                if (wv == 8) ring[(t - 1) & (RINGD - 1)][lane] = h;
            }
            // waves 9-11: batched projection of 16 finished timesteps
            if (wv >= 9 && (t & 15) == 1 && t >= 17) {
                const int o   = wv - 9;
                const int tau = lane & 15;
                const int q   = lane >> 4;
                const int s   = (t - 17) + tau;          // s..s+15 all <= t-2
                const float* rrow = &ring[s & (RINGD - 1)][q * 16];
                float p = 0.f;
                #pragma unroll
                for (int i = 0; i < 16; ++i) p = fmaf(wproj[i], rrow[i], p);
                p += __shfl_xor(p, 16);
                p += __shfl_xor(p, 32);
                if (q == 0) ob[(size_t)s * 3 + o] = p + bo;
            }
        }
        // single barrier/iter: DOT(t+1) reads only wave-private h bufs;
        // gate bufs parity-dbuf'd; ring read-set stays >=1 barrier old.
    }
}

extern "C" void kernel_launch(void* const* d_in, const int* in_sizes, int n_in,
                              void* d_out, int out_size, void* d_ws, size_t ws_size,
                              hipStream_t stream) {
    const float* x     = (const float*)d_in[0];
    const float* W_ih0 = (const float*)d_in[1];
    const float* W_hh0 = (const float*)d_in[2];
    const float* b_ih0 = (const float*)d_in[3];
    const float* b_hh0 = (const float*)d_in[4];
    const float* W_ih1 = (const float*)d_in[5];
    const float* W_hh1 = (const float*)d_in[6];
    const float* b_ih1 = (const float*)d_in[7];
    const float* b_hh1 = (const float*)d_in[8];
    const float* W_out = (const float*)d_in[9];
    const float* b_out = (const float*)d_in[10];
    float* out = (float*)d_out;

    const int B = in_sizes[0] / (TLEN * 3);   // 256
    hipLaunchKernelGGL(lstm_fused, dim3(B), dim3(768), 0, stream,
                       x, W_ih0, W_hh0, b_ih0, b_hh0,
                       W_ih1, W_hh1, b_ih1, b_hh1, W_out, b_out, out);
}

// Round 13
// 1637.289 us; speedup vs baseline: 5.1016x; 4.6780x over previous
//
#include <hip/hip_runtime.h>

#define HID   64
#define TLEN  1024
#define NGATE 256   // 4*HID
#define RINGD 32    // h1 history ring depth
#define RINGP 65    // padded cols (bank spread)
#define LOG2E 1.4426950408889634f

__device__ __forceinline__ float fast_rcp(float x) { return __builtin_amdgcn_rcpf(x); }
__device__ __forceinline__ float fexp2(float x)    { return __builtin_amdgcn_exp2f(x); }

__device__ __forceinline__ float fsig(float x) {
    return fast_rcp(1.0f + fexp2(-LOG2E * x));
}
__device__ __forceinline__ float ftanh(float x) {
    return fmaf(-2.0f, fast_rcp(1.0f + fexp2((2.0f * LOG2E) * x)), 1.0f);
}

// One workgroup per batch element (grid=256=#CUs). 768 threads = 12 waves,
// 3 waves/EU. REGISTER DISCIPLINE (hard-won, R3-R9): the ONLY proven
// register-resident shape is w[64] pins + scalar state at 768thr/(3,3)
// -> VGPR=84, FETCH 3.9MB (R5). Adding 16 more pinned floats (R9 wproj)
// silently spilled PINNED values -> 710MB/dispatch scratch storm, 7659us.
// So: nothing else gets pinned; projection weights live in LDS.
//
//   waves 0-3  (role0): g0 rows (W_hh0 row + W_ih0[r][:], fused bias)
//   waves 4-7  (role1): u1 rows (W_ih1 row, fused bias)
//   waves 8-11 (role2): v1 rows (W_hh1 row); waves 9-11 also run the
//                       batched output projection (weights from LDS)
//
// Single barrier per step: DOT(t) -> barrier -> COMBINE(t).
//   DOT(t):    role0 g0(t); role1 u1(t) from h0(t-1); role2 v1(t) from h1(t-2)
//              (h from wave-PRIVATE LDS copies; gate bufs parity-dbuf'd)
//   COMBINE(t): waves 0-7 redundantly combine layer0 -> own h0priv
//               waves 8-11 redundantly combine layer1 -> own h1priv;
//                 wave 8 also writes h1[t-1] -> ring[(t-1)&31]
//               waves 9-11, every 16 steps (t%16==1, t>=17): out[s][o] for
//                 s in [t-17, t-2] via transposed matvec on ring
//                 (lane=tau+16q: 16-elem partial dot, 2-level shfl).
// Race audit: slot t-1 (being written) not in read set; oldest read slot
// rewritten at t+16; write->read of slot t-2 crosses exactly 1 barrier;
// gate-buf parity hazard separated by >=1 barrier (slow reader blocks it).
__global__ __launch_bounds__(768)
__attribute__((amdgpu_waves_per_eu(3, 3)))
void lstm_fused(const float* __restrict__ x,
                const float* __restrict__ W_ih0, const float* __restrict__ W_hh0,
                const float* __restrict__ b_ih0, const float* __restrict__ b_hh0,
                const float* __restrict__ W_ih1, const float* __restrict__ W_hh1,
                const float* __restrict__ b_ih1, const float* __restrict__ b_hh1,
                const float* __restrict__ W_out, const float* __restrict__ b_out,
                float* __restrict__ out)
{
    __shared__ __align__(16) float x_lds[TLEN * 3];     // 12 KB
    __shared__ __align__(16) float g0buf[2][NGATE];     // 2 KB (parity dbuf)
    __shared__ __align__(16) float u1buf[2][NGATE];     // 2 KB
    __shared__ __align__(16) float v1buf[2][NGATE];     // 2 KB
    __shared__ __align__(16) float h0priv[8][HID];      // 2 KB (waves 0-7)
    __shared__ __align__(16) float h1priv[4][HID];      // 1 KB (waves 8-11)
    __shared__ __align__(16) float ring[RINGD][RINGP];  // 8.1 KB h1 history
    __shared__ __align__(16) float wout_lds[3 * HID];   // 768 B

    const int tid  = threadIdx.x;
    const int lane = tid & 63;
    const int wv   = tid >> 6;      // 0..11
    const int role = tid >> 8;      // 0..2
    const int r    = tid & 255;
    const int bidx = blockIdx.x;

    const float* xb = x   + (size_t)bidx * TLEN * 3;
    float*       ob = out + (size_t)bidx * TLEN * 3;

    // ---- weight row into registers (64 VGPRs; the ONLY pinned array) ----
    const float* wrow;
    float bias = 0.0f, wi0 = 0.f, wi1 = 0.f, wi2 = 0.f;
    if (role == 0) {
        wrow = W_hh0 + r * HID; bias = b_ih0[r] + b_hh0[r];
        wi0 = W_ih0[r*3+0]; wi1 = W_ih0[r*3+1]; wi2 = W_ih0[r*3+2];
    } else if (role == 1) {
        wrow = W_ih1 + r * HID; bias = b_ih1[r] + b_hh1[r];
    } else {
        wrow = W_hh1 + r * HID;
    }
    float w[HID];
    #pragma unroll
    for (int k4 = 0; k4 < HID / 4; ++k4) {
        float4 v = reinterpret_cast<const float4*>(wrow)[k4];
        w[4*k4+0] = v.x; w[4*k4+1] = v.y; w[4*k4+2] = v.z; w[4*k4+3] = v.w;
    }
    #pragma unroll
    for (int k = 0; k < HID; ++k) asm volatile("" : "+v"(w[k]));

    // projection bias only (1 scalar, no array pins)
    float bo = 0.f;
    if (wv >= 9 && wv <= 11) bo = b_out[wv - 9];

    // ---- stage x and W_out into LDS; init h bufs ----
    if (tid < (TLEN * 3) / 4)
        reinterpret_cast<float4*>(x_lds)[tid] = reinterpret_cast<const float4*>(xb)[tid];
    if (tid < 3 * HID) wout_lds[tid] = W_out[tid];
    if (tid < 8 * HID) (&h0priv[0][0])[tid] = 0.0f;
    if (tid < 4 * HID) (&h1priv[0][0])[tid] = 0.0f;
    float cst = 0.0f;   // c0 for waves 0-7, c1 for waves 8-11 (per-lane elem)
    __syncthreads();

    float x0 = 0.f, x1 = 0.f, x2 = 0.f;
    if (role == 0) { x0 = x_lds[0]; x1 = x_lds[1]; x2 = x_lds[2]; }

    for (int t = 0; t <= TLEN + 1; ++t) {
        const int par = t & 1;
        // ================= DOT phase =================
        if (role == 0) {
            if (t < TLEN) {
                const float4* h4 = reinterpret_cast<const float4*>(h0priv[wv]);
                float a0 = fmaf(wi0, x0, bias);
                float a1 = wi1 * x1, a2 = wi2 * x2, a3 = 0.0f;
                #pragma unroll
                for (int k4 = 0; k4 < HID / 4; ++k4) {
                    float4 hv = h4[k4];
                    a0 = fmaf(w[4*k4+0], hv.x, a0);
                    a1 = fmaf(w[4*k4+1], hv.y, a1);
                    a2 = fmaf(w[4*k4+2], hv.z, a2);
                    a3 = fmaf(w[4*k4+3], hv.w, a3);
                }
                g0buf[par][r] = (a0 + a1) + (a2 + a3);
            }
        } else if (role == 1) {
            if (t <= TLEN) {
                const float4* h4 = reinterpret_cast<const float4*>(h0priv[wv]);
                float a0 = bias, a1 = 0.f, a2 = 0.f, a3 = 0.f;
                #pragma unroll
                for (int k4 = 0; k4 < HID / 4; ++k4) {
                    float4 hv = h4[k4];
                    a0 = fmaf(w[4*k4+0], hv.x, a0);
                    a1 = fmaf(w[4*k4+1], hv.y, a1);
                    a2 = fmaf(w[4*k4+2], hv.z, a2);
                    a3 = fmaf(w[4*k4+3], hv.w, a3);
                }
                u1buf[par][r] = (a0 + a1) + (a2 + a3);
            }
        } else {
            if (t <= TLEN) {
                const float4* h4 = reinterpret_cast<const float4*>(h1priv[wv - 8]);
                float a0 = 0.f, a1 = 0.f, a2 = 0.f, a3 = 0.f;
                #pragma unroll
                for (int k4 = 0; k4 < HID / 4; ++k4) {
                    float4 hv = h4[k4];
                    a0 = fmaf(w[4*k4+0], hv.x, a0);
                    a1 = fmaf(w[4*k4+1], hv.y, a1);
                    a2 = fmaf(w[4*k4+2], hv.z, a2);
                    a3 = fmaf(w[4*k4+3], hv.w, a3);
                }
                v1buf[par][r] = (a0 + a1) + (a2 + a3);
            }
        }
        __syncthreads();
        // ================= COMBINE phase =================
        if (role <= 1) {                     // waves 0-7: layer-0 combine
            if (t < TLEN) {
                float gi = fsig (g0buf[par][lane]);
                float gf = fsig (g0buf[par][ 64 + lane]);
                float gg = ftanh(g0buf[par][128 + lane]);
                float go = fsig (g0buf[par][192 + lane]);
                cst = fmaf(gf, cst, gi * gg);
                h0priv[wv][lane] = go * ftanh(cst);
                if (role == 0) {             // prefetch x[t+1]
                    int tx = (t + 1 < TLEN) ? t + 1 : 0;
                    x0 = x_lds[3*tx]; x1 = x_lds[3*tx+1]; x2 = x_lds[3*tx+2];
                }
            }
        } else {                             // waves 8-11: layer-1 combine
            if (t >= 1 && t <= TLEN) {
                float gi = fsig (u1buf[par][lane]       + v1buf[par][lane]);
                float gf = fsig (u1buf[par][ 64 + lane] + v1buf[par][ 64 + lane]);
                float gg = ftanh(u1buf[par][128 + lane] + v1buf[par][128 + lane]);
                float go = fsig (u1buf[par][192 + lane] + v1buf[par][192 + lane]);
                cst = fmaf(gf, cst, gi * gg);
                float h = go * ftanh(cst);
                h1priv[wv - 8][lane] = h;
                if (wv == 8) ring[(t - 1) & (RINGD - 1)][lane] = h;
            }
            // waves 9-11: batched projection of 16 finished timesteps
            if (wv >= 9 && (t & 15) == 1 && t >= 17) {
                const int o   = wv - 9;
                const int tau = lane & 15;
                const int q   = lane >> 4;
                const int s   = (t - 17) + tau;          // s..s+15 all <= t-2
                const float* rrow = &ring[s & (RINGD - 1)][q * 16];
                const float* wp   = &wout_lds[o * HID + q * 16];
                float p = 0.f;
                #pragma unroll
                for (int i = 0; i < 16; ++i) p = fmaf(wp[i], rrow[i], p);
                p += __shfl_xor(p, 16);
                p += __shfl_xor(p, 32);
                if (q == 0) ob[(size_t)s * 3 + o] = p + bo;
            }
        }
        // single barrier/iter: DOT(t+1) reads only wave-private h bufs;
        // gate bufs parity-dbuf'd; ring read-set stays >=1 barrier old.
    }
}

extern "C" void kernel_launch(void* const* d_in, const int* in_sizes, int n_in,
                              void* d_out, int out_size, void* d_ws, size_t ws_size,
                              hipStream_t stream) {
    const float* x     = (const float*)d_in[0];
    const float* W_ih0 = (const float*)d_in[1];
    const float* W_hh0 = (const float*)d_in[2];
    const float* b_ih0 = (const float*)d_in[3];
    const float* b_hh0 = (const float*)d_in[4];
    const float* W_ih1 = (const float*)d_in[5];
    const float* W_hh1 = (const float*)d_in[6];
    const float* b_ih1 = (const float*)d_in[7];
    const float* b_hh1 = (const float*)d_in[8];
    const float* W_out = (const float*)d_in[9];
    const float* b_out = (const float*)d_in[10];
    float* out = (float*)d_out;

    const int B = in_sizes[0] / (TLEN * 3);   // 256
    hipLaunchKernelGGL(lstm_fused, dim3(B), dim3(768), 0, stream,
                       x, W_ih0, W_hh0, b_ih0, b_hh0,
                       W_ih1, W_hh1, b_ih1, b_hh1, W_out, b_out, out);
}

// Round 14
// 1131.532 us; speedup vs baseline: 7.3819x; 1.4470x over previous
//
#include <hip/hip_runtime.h>

#define HID   64
#define TLEN  1024
#define NGATE 256   // 4*HID
#define RINGD 32    // h1 history ring depth
#define RINGP 65    // padded cols (bank spread)
#define LOG2E 1.4426950408889634f

__device__ __forceinline__ float fast_rcp(float x) { return __builtin_amdgcn_rcpf(x); }
__device__ __forceinline__ float fexp2(float x)    { return __builtin_amdgcn_exp2f(x); }

__device__ __forceinline__ float fsig(float x) {
    return fast_rcp(1.0f + fexp2(-LOG2E * x));
}
__device__ __forceinline__ float ftanh(float x) {
    return fmaf(-2.0f, fast_rcp(1.0f + fexp2((2.0f * LOG2E) * x)), 1.0f);
}

// lane-k broadcast via SGPR (VALU-only, no LDS)
__device__ __forceinline__ float blane(float v, int k) {
    return __uint_as_float(__builtin_amdgcn_readlane(__float_as_uint(v), k));
}

// One workgroup per batch element (grid=256=#CUs). 768 threads = 12 waves,
// 3 waves/EU. REGISTER DISCIPLINE (R3-R9): w[64] pins + scalars at
// 768thr/(3,3) -> VGPR=84 resident (R5/R13). Nothing else gets pinned.
//
// R13 measured: single-barrier schedule = 1692us (-25% vs 2-barrier 2250).
// Remaining floor theory: DOT's LDS h-broadcast latency (16x ds_read_b128 +
// lgkm per wave per step). THIS ROUND: h lives in registers, lane j = h[j]
// (every wave already computes its layer's combine redundantly). DOT uses
// v_readlane SGPR broadcast: fma(w[k], readlane(hreg,k), acc) -- zero LDS
// ops in DOT. h0priv/h1priv deleted. Gate exchange (cross-wave) keeps the
// single barrier; parity dbuf + ring race distances unchanged from R13.
//
//   waves 0-3  (role0): g0 rows (W_hh0 row + W_ih0[r][:], fused bias)
//   waves 4-7  (role1): u1 rows (W_ih1 row, fused bias)
//   waves 8-11 (role2): v1 rows (W_hh1 row); waves 9-11 also batched
//                       projection every 16 steps (weights from LDS)
__global__ __launch_bounds__(768)
__attribute__((amdgpu_waves_per_eu(3, 3)))
void lstm_fused(const float* __restrict__ x,
                const float* __restrict__ W_ih0, const float* __restrict__ W_hh0,
                const float* __restrict__ b_ih0, const float* __restrict__ b_hh0,
                const float* __restrict__ W_ih1, const float* __restrict__ W_hh1,
                const float* __restrict__ b_ih1, const float* __restrict__ b_hh1,
                const float* __restrict__ W_out, const float* __restrict__ b_out,
                float* __restrict__ out)
{
    __shared__ __align__(16) float x_lds[TLEN * 3];     // 12 KB
    __shared__ __align__(16) float g0buf[2][NGATE];     // 2 KB (parity dbuf)
    __shared__ __align__(16) float u1buf[2][NGATE];     // 2 KB
    __shared__ __align__(16) float v1buf[2][NGATE];     // 2 KB
    __shared__ __align__(16) float ring[RINGD][RINGP];  // 8.1 KB h1 history
    __shared__ __align__(16) float wout_lds[3 * HID];   // 768 B

    const int tid  = threadIdx.x;
    const int lane = tid & 63;
    const int wv   = tid >> 6;      // 0..11
    const int role = tid >> 8;      // 0..2
    const int r    = tid & 255;
    const int bidx = blockIdx.x;

    const float* xb = x   + (size_t)bidx * TLEN * 3;
    float*       ob = out + (size_t)bidx * TLEN * 3;

    // ---- weight row into registers (64 VGPRs; the ONLY pinned array) ----
    const float* wrow;
    float bias = 0.0f, wi0 = 0.f, wi1 = 0.f, wi2 = 0.f;
    if (role == 0) {
        wrow = W_hh0 + r * HID; bias = b_ih0[r] + b_hh0[r];
        wi0 = W_ih0[r*3+0]; wi1 = W_ih0[r*3+1]; wi2 = W_ih0[r*3+2];
    } else if (role == 1) {
        wrow = W_ih1 + r * HID; bias = b_ih1[r] + b_hh1[r];
    } else {
        wrow = W_hh1 + r * HID;
    }
    float w[HID];
    #pragma unroll
    for (int k4 = 0; k4 < HID / 4; ++k4) {
        float4 v = reinterpret_cast<const float4*>(wrow)[k4];
        w[4*k4+0] = v.x; w[4*k4+1] = v.y; w[4*k4+2] = v.z; w[4*k4+3] = v.w;
    }
    #pragma unroll
    for (int k = 0; k < HID; ++k) asm volatile("" : "+v"(w[k]));

    // projection bias only (1 scalar, no array pins)
    float bo = 0.f;
    if (wv >= 9 && wv <= 11) bo = b_out[wv - 9];

    // ---- stage x and W_out into LDS ----
    if (tid < (TLEN * 3) / 4)
        reinterpret_cast<float4*>(x_lds)[tid] = reinterpret_cast<const float4*>(xb)[tid];
    if (tid < 3 * HID) wout_lds[tid] = W_out[tid];
    float cst  = 0.0f;   // per-lane cell state (c0 waves 0-7, c1 waves 8-11)
    float hreg = 0.0f;   // per-lane hidden  (h0 waves 0-7, h1 waves 8-11)
    __syncthreads();

    float x0 = 0.f, x1 = 0.f, x2 = 0.f;
    if (role == 0) { x0 = x_lds[0]; x1 = x_lds[1]; x2 = x_lds[2]; }

    for (int t = 0; t <= TLEN + 1; ++t) {
        const int par = t & 1;
        // ================= DOT phase (register broadcast, no LDS) =========
        if (role == 0) {
            if (t < TLEN) {
                float a0 = fmaf(wi0, x0, bias);
                float a1 = wi1 * x1, a2 = wi2 * x2, a3 = 0.0f;
                #pragma unroll
                for (int k = 0; k < HID; k += 4) {
                    a0 = fmaf(w[k+0], blane(hreg, k+0), a0);
                    a1 = fmaf(w[k+1], blane(hreg, k+1), a1);
                    a2 = fmaf(w[k+2], blane(hreg, k+2), a2);
                    a3 = fmaf(w[k+3], blane(hreg, k+3), a3);
                }
                g0buf[par][r] = (a0 + a1) + (a2 + a3);
            }
        } else if (role == 1) {
            if (t <= TLEN) {
                float a0 = bias, a1 = 0.f, a2 = 0.f, a3 = 0.f;
                #pragma unroll
                for (int k = 0; k < HID; k += 4) {
                    a0 = fmaf(w[k+0], blane(hreg, k+0), a0);
                    a1 = fmaf(w[k+1], blane(hreg, k+1), a1);
                    a2 = fmaf(w[k+2], blane(hreg, k+2), a2);
                    a3 = fmaf(w[k+3], blane(hreg, k+3), a3);
                }
                u1buf[par][r] = (a0 + a1) + (a2 + a3);
            }
        } else {
            if (t <= TLEN) {
                float a0 = 0.f, a1 = 0.f, a2 = 0.f, a3 = 0.f;
                #pragma unroll
                for (int k = 0; k < HID; k += 4) {
                    a0 = fmaf(w[k+0], blane(hreg, k+0), a0);
                    a1 = fmaf(w[k+1], blane(hreg, k+1), a1);
                    a2 = fmaf(w[k+2], blane(hreg, k+2), a2);
                    a3 = fmaf(w[k+3], blane(hreg, k+3), a3);
                }
                v1buf[par][r] = (a0 + a1) + (a2 + a3);
            }
        }
        __syncthreads();
        // ================= COMBINE phase =================
        if (role <= 1) {                     // waves 0-7: layer-0 combine
            if (t < TLEN) {
                float gi = fsig (g0buf[par][lane]);
                float gf = fsig (g0buf[par][ 64 + lane]);
                float gg = ftanh(g0buf[par][128 + lane]);
                float go = fsig (g0buf[par][192 + lane]);
                cst  = fmaf(gf, cst, gi * gg);
                hreg = go * ftanh(cst);      // h0(t), stays in register
                if (role == 0) {             // prefetch x[t+1]
                    int tx = (t + 1 < TLEN) ? t + 1 : 0;
                    x0 = x_lds[3*tx]; x1 = x_lds[3*tx+1]; x2 = x_lds[3*tx+2];
                }
            }
        } else {                             // waves 8-11: layer-1 combine
            if (t >= 1 && t <= TLEN) {
                float gi = fsig (u1buf[par][lane]       + v1buf[par][lane]);
                float gf = fsig (u1buf[par][ 64 + lane] + v1buf[par][ 64 + lane]);
                float gg = ftanh(u1buf[par][128 + lane] + v1buf[par][128 + lane]);
                float go = fsig (u1buf[par][192 + lane] + v1buf[par][192 + lane]);
                cst  = fmaf(gf, cst, gi * gg);
                hreg = go * ftanh(cst);      // h1(t-1), stays in register
                if (wv == 8) ring[(t - 1) & (RINGD - 1)][lane] = hreg;
            }
            // waves 9-11: batched projection of 16 finished timesteps
            if (wv >= 9 && (t & 15) == 1 && t >= 17) {
                const int o   = wv - 9;
                const int tau = lane & 15;
                const int q   = lane >> 4;
                const int s   = (t - 17) + tau;          // s..s+15 all <= t-2
                const float* rrow = &ring[s & (RINGD - 1)][q * 16];
                const float* wp   = &wout_lds[o * HID + q * 16];
                float p = 0.f;
                #pragma unroll
                for (int i = 0; i < 16; ++i) p = fmaf(wp[i], rrow[i], p);
                p += __shfl_xor(p, 16);
                p += __shfl_xor(p, 32);
                if (q == 0) ob[(size_t)s * 3 + o] = p + bo;
            }
        }
        // single barrier/iter: DOT(t+1) reads only registers (hreg);
        // gate bufs parity-dbuf'd; ring read-set stays >=1 barrier old.
    }
}

extern "C" void kernel_launch(void* const* d_in, const int* in_sizes, int n_in,
                              void* d_out, int out_size, void* d_ws, size_t ws_size,
                              hipStream_t stream) {
    const float* x     = (const float*)d_in[0];
    const float* W_ih0 = (const float*)d_in[1];
    const float* W_hh0 = (const float*)d_in[2];
    const float* b_ih0 = (const float*)d_in[3];
    const float* b_hh0 = (const float*)d_in[4];
    const float* W_ih1 = (const float*)d_in[5];
    const float* W_hh1 = (const float*)d_in[6];
    const float* b_ih1 = (const float*)d_in[7];
    const float* b_hh1 = (const float*)d_in[8];
    const float* W_out = (const float*)d_in[9];
    const float* b_out = (const float*)d_in[10];
    float* out = (float*)d_out;

    const int B = in_sizes[0] / (TLEN * 3);   // 256
    hipLaunchKernelGGL(lstm_fused, dim3(B), dim3(768), 0, stream,
                       x, W_ih0, W_hh0, b_ih0, b_hh0,
                       W_ih1, W_hh1, b_ih1, b_hh1, W_out, b_out, out);
}

// Round 16
// 835.347 us; speedup vs baseline: 9.9992x; 1.3546x over previous
//
#include <hip/hip_runtime.h>

#define HID   64
#define TLEN  1024
#define NGATE 256   // 4*HID
#define RINGD 32    // h1 history ring depth
#define RINGP 65    // padded cols (bank spread)
#define LOG2E 1.4426950408889634f

__device__ __forceinline__ float fast_rcp(float x) { return __builtin_amdgcn_rcpf(x); }
__device__ __forceinline__ float fexp2(float x)    { return __builtin_amdgcn_exp2f(x); }

__device__ __forceinline__ float fsig(float x) {
    return fast_rcp(1.0f + fexp2(-LOG2E * x));
}
__device__ __forceinline__ float ftanh(float x) {
    return fmaf(-2.0f, fast_rcp(1.0f + fexp2((2.0f * LOG2E) * x)), 1.0f);
}

// lane-k broadcast via SGPR (VALU-only, no LDS)
__device__ __forceinline__ float blane(float v, int k) {
    return __uint_as_float(__builtin_amdgcn_readlane(__float_as_uint(v), k));
}

// ALLOCATOR LAW (empirical R3-R14): with amdgpu_waves_per_eu(N,N) the
// allocator caps VGPRs at 512/(2N) and SPILLS demand above it (R9 storm):
// (3,3)->84 (R5/R9/R13), (4,4)->64 (R8). This kernel needs ~155 VGPRs
// (two 64-row weight arrays in waves 0-3), so (1,1) -> predicted cap 256.
//
// 8 waves (512 threads), grid=256=#CUs, 1 block/CU:
//   waves 0-3 (A): DUAL-ROLE rows r=tid&255: g0 = W_hh0[r]@h0 (+x,bias) AND
//                  u1 = W_ih1[r]@h0 (+bias) -- ONE readlane set feeds BOTH
//                  dots (halves broadcast overhead vs 12-wave R14).
//                  Combine layer0 redundantly -> hreg (lane j = h0[j]).
//   waves 4-7 (C): v1 = W_hh1[r]@h1; combine layer1 -> hreg; wave 4 writes
//                  ring; waves 5-7 batched projection every 16 steps.
// Single barrier/step, parity-dbuf'd gate bufs (R13), register-h (R14).
//
// R15 BUG (fixed here): A-waves' single t<TLEN guard skipped u1(TLEN),
// which the final layer-1 combine (h1(TLEN-1)) needs -> out[TLEN-1] was
// stale (absmax 1.2e-2). Now: A DOT runs t<=TLEN; g0 store gated t<TLEN,
// u1 store always. (R14's role1 guard was t<=TLEN for exactly this reason.)
__global__ __launch_bounds__(512)
__attribute__((amdgpu_waves_per_eu(1, 1)))
void lstm_fused(const float* __restrict__ x,
                const float* __restrict__ W_ih0, const float* __restrict__ W_hh0,
                const float* __restrict__ b_ih0, const float* __restrict__ b_hh0,
                const float* __restrict__ W_ih1, const float* __restrict__ W_hh1,
                const float* __restrict__ b_ih1, const float* __restrict__ b_hh1,
                const float* __restrict__ W_out, const float* __restrict__ b_out,
                float* __restrict__ out)
{
    __shared__ __align__(16) float x_lds[TLEN * 3];     // 12 KB
    __shared__ __align__(16) float g0buf[2][NGATE];     // 2 KB (parity dbuf)
    __shared__ __align__(16) float u1buf[2][NGATE];     // 2 KB
    __shared__ __align__(16) float v1buf[2][NGATE];     // 2 KB
    __shared__ __align__(16) float ring[RINGD][RINGP];  // 8.1 KB h1 history
    __shared__ __align__(16) float wout_lds[3 * HID];   // 768 B

    const int tid  = threadIdx.x;
    const int lane = tid & 63;
    const int wv   = tid >> 6;      // 0..7
    const bool isA = (wv < 4);
    const int r    = tid & 255;     // row for both A (g0/u1) and C (v1)
    const int bidx = blockIdx.x;

    const float* xb = x   + (size_t)bidx * TLEN * 3;
    float*       ob = out + (size_t)bidx * TLEN * 3;

    // ---- weight rows into registers ----
    // A: w0 = W_hh0[r], w1 = W_ih1[r].  C: w0 = W_hh1[r], w1 = dup (dead).
    const float* wrow0 = isA ? (W_hh0 + r * HID) : (W_hh1 + r * HID);
    const float* wrow1 = isA ? (W_ih1 + r * HID) : (W_hh1 + r * HID);
    float bias0 = 0.f, bias1 = 0.f, wi0 = 0.f, wi1 = 0.f, wi2 = 0.f;
    if (isA) {
        bias0 = b_ih0[r] + b_hh0[r];
        bias1 = b_ih1[r] + b_hh1[r];
        wi0 = W_ih0[r*3+0]; wi1 = W_ih0[r*3+1]; wi2 = W_ih0[r*3+2];
    }
    float w0[HID], w1[HID];
    #pragma unroll
    for (int k4 = 0; k4 < HID / 4; ++k4) {
        float4 a = reinterpret_cast<const float4*>(wrow0)[k4];
        float4 b = reinterpret_cast<const float4*>(wrow1)[k4];
        w0[4*k4+0] = a.x; w0[4*k4+1] = a.y; w0[4*k4+2] = a.z; w0[4*k4+3] = a.w;
        w1[4*k4+0] = b.x; w1[4*k4+1] = b.y; w1[4*k4+2] = b.z; w1[4*k4+3] = b.w;
    }
    #pragma unroll
    for (int k = 0; k < HID; ++k) asm volatile("" : "+v"(w0[k]));
    #pragma unroll
    for (int k = 0; k < HID; ++k) asm volatile("" : "+v"(w1[k]));

    // projection bias (waves 5-7)
    float bo = 0.f;
    if (wv >= 5 && wv <= 7) bo = b_out[wv - 5];

    // ---- stage x and W_out into LDS ----
    for (int i = tid; i < (TLEN * 3) / 4; i += 512)
        reinterpret_cast<float4*>(x_lds)[i] = reinterpret_cast<const float4*>(xb)[i];
    if (tid < 3 * HID) wout_lds[tid] = W_out[tid];
    float cst  = 0.0f;   // per-lane cell state (c0 for A, c1 for C)
    float hreg = 0.0f;   // per-lane hidden  (h0 for A, h1 for C)
    __syncthreads();

    float x0 = 0.f, x1 = 0.f, x2 = 0.f;
    if (isA) { x0 = x_lds[0]; x1 = x_lds[1]; x2 = x_lds[2]; }

    #pragma unroll 2
    for (int t = 0; t <= TLEN + 1; ++t) {
        const int par = t & 1;
        // ================= DOT phase (register broadcast, no LDS) =========
        if (isA) {
            if (t <= TLEN) {                 // u1 needed through t==TLEN
                float g0_ = fmaf(wi0, x0, bias0);
                float g1_ = wi1 * x1, g2_ = wi2 * x2, g3_ = 0.0f;
                float u0_ = bias1, u1_ = 0.f, u2_ = 0.f, u3_ = 0.f;
                #pragma unroll
                for (int k = 0; k < HID; k += 4) {
                    float h0 = blane(hreg, k+0);
                    float h1 = blane(hreg, k+1);
                    float h2 = blane(hreg, k+2);
                    float h3 = blane(hreg, k+3);
                    g0_ = fmaf(w0[k+0], h0, g0_);
                    g1_ = fmaf(w0[k+1], h1, g1_);
                    g2_ = fmaf(w0[k+2], h2, g2_);
                    g3_ = fmaf(w0[k+3], h3, g3_);
                    u0_ = fmaf(w1[k+0], h0, u0_);
                    u1_ = fmaf(w1[k+1], h1, u1_);
                    u2_ = fmaf(w1[k+2], h2, u2_);
                    u3_ = fmaf(w1[k+3], h3, u3_);
                }
                if (t < TLEN) g0buf[par][r] = (g0_ + g1_) + (g2_ + g3_);
                u1buf[par][r] = (u0_ + u1_) + (u2_ + u3_);   // incl. t==TLEN
            }
        } else {
            if (t <= TLEN) {
                float a0 = 0.f, a1 = 0.f, a2 = 0.f, a3 = 0.f;
                #pragma unroll
                for (int k = 0; k < HID; k += 4) {
                    a0 = fmaf(w0[k+0], blane(hreg, k+0), a0);
                    a1 = fmaf(w0[k+1], blane(hreg, k+1), a1);
                    a2 = fmaf(w0[k+2], blane(hreg, k+2), a2);
                    a3 = fmaf(w0[k+3], blane(hreg, k+3), a3);
                }
                v1buf[par][r] = (a0 + a1) + (a2 + a3);
            }
        }
        __syncthreads();
        // ================= COMBINE phase =================
        if (isA) {                            // waves 0-3: layer-0 combine
            if (t < TLEN) {
                float gi = fsig (g0buf[par][lane]);
                float gf = fsig (g0buf[par][ 64 + lane]);
                float gg = ftanh(g0buf[par][128 + lane]);
                float go = fsig (g0buf[par][192 + lane]);
                cst  = fmaf(gf, cst, gi * gg);
                hreg = go * ftanh(cst);       // h0(t), stays in register
                int tx = (t + 1 < TLEN) ? t + 1 : 0;   // prefetch x[t+1]
                x0 = x_lds[3*tx]; x1 = x_lds[3*tx+1]; x2 = x_lds[3*tx+2];
            }
        } else {                              // waves 4-7: layer-1 combine
            if (t >= 1 && t <= TLEN) {
                float gi = fsig (u1buf[par][lane]       + v1buf[par][lane]);
                float gf = fsig (u1buf[par][ 64 + lane] + v1buf[par][ 64 + lane]);
                float gg = ftanh(u1buf[par][128 + lane] + v1buf[par][128 + lane]);
                float go = fsig (u1buf[par][192 + lane] + v1buf[par][192 + lane]);
                cst  = fmaf(gf, cst, gi * gg);
                hreg = go * ftanh(cst);       // h1(t-1), stays in register
                if (wv == 4) ring[(t - 1) & (RINGD - 1)][lane] = hreg;
            }
            // waves 5-7: batched projection of 16 finished timesteps
            if (wv >= 5 && (t & 15) == 1 && t >= 17) {
                const int o   = wv - 5;
                const int tau = lane & 15;
                const int q   = lane >> 4;
                const int s   = (t - 17) + tau;          // s..s+15 all <= t-2
                const float* rrow = &ring[s & (RINGD - 1)][q * 16];
                const float* wp   = &wout_lds[o * HID + q * 16];
                float p = 0.f;
                #pragma unroll
                for (int i = 0; i < 16; ++i) p = fmaf(wp[i], rrow[i], p);
                p += __shfl_xor(p, 16);
                p += __shfl_xor(p, 32);
                if (q == 0) ob[(size_t)s * 3 + o] = p + bo;
            }
        }
        // single barrier/iter: DOT(t+1) reads only registers (hreg);
        // gate bufs parity-dbuf'd; ring read-set stays >=1 barrier old.
    }
}

extern "C" void kernel_launch(void* const* d_in, const int* in_sizes, int n_in,
                              void* d_out, int out_size, void* d_ws, size_t ws_size,
                              hipStream_t stream) {
    const float* x     = (const float*)d_in[0];
    const float* W_ih0 = (const float*)d_in[1];
    const float* W_hh0 = (const float*)d_in[2];
    const float* b_ih0 = (const float*)d_in[3];
    const float* b_hh0 = (const float*)d_in[4];
    const float* W_ih1 = (const float*)d_in[5];
    const float* W_hh1 = (const float*)d_in[6];
    const float* b_ih1 = (const float*)d_in[7];
    const float* b_hh1 = (const float*)d_in[8];
    const float* W_out = (const float*)d_in[9];
    const float* b_out = (const float*)d_in[10];
    float* out = (float*)d_out;

    const int B = in_sizes[0] / (TLEN * 3);   // 256
    hipLaunchKernelGGL(lstm_fused, dim3(B), dim3(512), 0, stream,
                       x, W_ih0, W_hh0, b_ih0, b_hh0,
                       W_ih1, W_hh1, b_ih1, b_hh1, W_out, b_out, out);
}